// Round 11
// baseline (181.007 us; speedup 1.0000x reference)
//
#include <hip/hip_runtime.h>
#include <stdint.h>

#define Bn 8
#define Nn 1024
#define Fn 64
#define Tn 32
#define Kn 3
#define On 64
#define Rn (Kn * Nn)   // 3072 reduction dim (k,j)
#define Cn (On * Tn)   // 2048 output cols (o,t)
#define NT (Rn / 64)   // 48 K-tiles of BK=64

typedef __bf16 bf16x8 __attribute__((ext_vector_type(8)));
typedef float f32x4 __attribute__((ext_vector_type(4)));
typedef __attribute__((address_space(1))) void gvoid;
typedef __attribute__((address_space(3))) void lvoid;

union BF8 { bf16x8 v; ushort s[8]; uint4 q; };

static __device__ __forceinline__ ushort f2bf(float f) {
  uint32_t u = __float_as_uint(f);
  return (ushort)((u + 0x7FFFu + ((u >> 16) & 1u)) >> 16);
}

static __device__ __forceinline__ void glds(const ushort* g, ushort* l) {
  __builtin_amdgcn_global_load_lds((gvoid*)g, (lvoid*)l, 16, 0, 0);
}

// K0: ThetaT[k][o][f] = Theta[k][f][o], bf16
__global__ void k_thetaT(const float* __restrict__ Theta, ushort* __restrict__ ThT) {
  int idx = blockIdx.x * 256 + threadIdx.x;
  if (idx < Kn * On * Fn) {
    int k = idx / (On * Fn);
    int rem = idx % (On * Fn);
    int o = rem / Fn, f = rem % Fn;
    ThT[idx] = f2bf(Theta[(k * Fn + f) * On + o]);
  }
}

// K1: Wt[b][i][k*Nn+j] = cheb[k][j][i] * att[b][j][i], bf16 (R9 version).
__global__ __launch_bounds__(256) void k_prepW(const float* __restrict__ att,
                                               const float* __restrict__ cheb,
                                               ushort* __restrict__ Wt) {
  __shared__ float chebT[Kn][64][33];
  __shared__ float attT[64][33];
  int i0 = blockIdx.x * 64, j0 = blockIdx.y * 32;
  int tid = threadIdx.x;
  int il = tid & 63, jr = tid >> 6;
  int jc = tid & 3, iw = tid >> 2;

#pragma unroll
  for (int k = 0; k < Kn; k++)
#pragma unroll
    for (int p = 0; p < 8; p++) {
      int j = jr + p * 4;
      chebT[k][il][j] = cheb[((size_t)k * Nn + j0 + j) * Nn + i0 + il];
    }

  for (int b = 0; b < Bn; b++) {
    __syncthreads();
#pragma unroll
    for (int p = 0; p < 8; p++) {
      int j = jr + p * 4;
      attT[il][j] = att[((size_t)b * Nn + j0 + j) * Nn + i0 + il];
    }
    __syncthreads();
#pragma unroll
    for (int k = 0; k < Kn; k++) {
      ushort tmp[8];
#pragma unroll
      for (int q = 0; q < 8; q++)
        tmp[q] = f2bf(attT[iw][jc * 8 + q] * chebT[k][iw][jc * 8 + q]);
      *(uint4*)&Wt[((size_t)b * Nn + i0 + iw) * Rn + (size_t)k * Nn + j0 + jc * 8] =
          *(const uint4*)tmp;
    }
  }
}

// K2: Y_T[b][c][k*Nn+j] = sum_f ThT[k][o][f]*x[b][j][f][t].
// R11: jj-PAIR batching — LDS writes packed to ds_write_b32 (was 64 scalar b16
// stores/thread per (k,h); now 32 b32). Global write pass unchanged (uint4).
__global__ __launch_bounds__(512) void k_prepY(const float* __restrict__ x,
                                               const ushort* __restrict__ ThT,
                                               ushort* __restrict__ Yt) {
  __shared__ ushort ylds[1024 * 32];
  int jt = blockIdx.x, b = blockIdx.y;
  int j0 = jt * 32;
  int tid = threadIdx.x;
  int lane = tid & 63, w = tid >> 6;
  int l15 = lane & 15, l4 = lane >> 4;

  BF8 bfr[4][2][2];
#pragma unroll
  for (int jj = 0; jj < 4; jj++) {
    const float* xp = x + ((size_t)b * Nn + (j0 + w * 4 + jj)) * (Fn * Tn);
#pragma unroll
    for (int ks = 0; ks < 2; ks++)
#pragma unroll
      for (int tf = 0; tf < 2; tf++) {
        int t = tf * 16 + l15;
        int fb = ks * 32 + l4 * 8;
#pragma unroll
        for (int e = 0; e < 8; e++)
          bfr[jj][ks][tf].s[e] = f2bf(xp[(fb + e) * Tn + t]);
      }
  }

  for (int k = 0; k < Kn; k++) {
    for (int h = 0; h < 2; h++) {
      BF8 afr[2][2];
#pragma unroll
      for (int o2 = 0; o2 < 2; o2++)
#pragma unroll
        for (int ks = 0; ks < 2; ks++) {
          int o = h * 32 + o2 * 16 + l15;
          afr[o2][ks].q = *(const uint4*)&ThT[((size_t)k * On + o) * Fn + ks * 32 + l4 * 8];
        }
      uint32_t* y32 = (uint32_t*)ylds;
#pragma unroll
      for (int jp = 0; jp < 2; jp++) {
        f32x4 acc[2][2][2] = {};  // [j2][o2][tf]
#pragma unroll
        for (int j2 = 0; j2 < 2; j2++)
#pragma unroll
          for (int ks = 0; ks < 2; ks++)
#pragma unroll
            for (int o2 = 0; o2 < 2; o2++)
#pragma unroll
              for (int tf = 0; tf < 2; tf++)
                acc[j2][o2][tf] = __builtin_amdgcn_mfma_f32_16x16x32_bf16(
                    afr[o2][ks].v, bfr[jp * 2 + j2][ks][tf].v, acc[j2][o2][tf], 0, 0, 0);
#pragma unroll
        for (int o2 = 0; o2 < 2; o2++)
#pragma unroll
          for (int tf = 0; tf < 2; tf++)
#pragma unroll
            for (int q = 0; q < 4; q++) {
              int cl = (o2 * 16 + l4 * 4 + q) * Tn + tf * 16 + l15;
              uint32_t pk = (uint32_t)f2bf(acc[0][o2][tf][q]) |
                            ((uint32_t)f2bf(acc[1][o2][tf][q]) << 16);
              y32[cl * 16 + w * 2 + jp] = pk;
            }
      }
      __syncthreads();
      const uint4* yl4 = (const uint4*)ylds;
      uint4* Yt4 = (uint4*)Yt;
      int e4 = tid & 3, r4 = tid >> 2;
      for (int pass = 0; pass < 8; pass++) {
        int cl = pass * 128 + r4;
        size_t off = ((size_t)b * Cn + (size_t)(h * 1024 + cl)) * Rn + (size_t)k * Nn + j0;
        Yt4[off / 8 + e4] = yl4[cl * 4 + e4];
      }
      __syncthreads();
    }
  }
}

// K3: 256x256, BK=64, 8 waves (2Mx4N), XOR-swizzled LDS, 2-deep dbuf.
// R11: R8's 8-phase skeleton with BALANCED reads 12/4/4/4 — quadrant = 2m x 4n,
// B-frags read once at P0 and held full-tile in regs. Staging/vmcnt queue
// identical to R8 (traced): A1(t+1)@P0, A0(t+2)@P1, B0(t+2)@P2, B1(t+2)@P3,
// single VMC(6)@P3.
__global__ __launch_bounds__(512, 2) void k_gemm(const ushort* __restrict__ Wt,
                                                 const ushort* __restrict__ Yt,
                                                 float* __restrict__ out) {
  extern __shared__ __align__(16) ushort smem[];
  ushort* As = smem;           // 2 bufs x 2 halves x 128x64
  ushort* Bs = smem + 32768;

  int g = blockIdx.x;
  int b = g & 7, slot = g >> 3;
  int i0 = (slot & 3) * 256, c0 = (slot >> 2) * 256;
  int tid = threadIdx.x, lane = tid & 63, w = tid >> 6;
  int l15 = lane & 15, l4 = lane >> 4;
  int wm = w >> 2, wn = w & 3;

  const ushort* Ab = Wt + ((size_t)b * Nn + i0) * Rn;
  const ushort* Bb = Yt + ((size_t)b * Cn + c0) * Rn;

  int srcC = (((lane & 7) ^ (lane >> 3)) * 8);
  int arow0 = w * 8 + (lane >> 3);
  int brow0 = (w >> 2) * 64 + (w & 3) * 8 + (lane >> 3);

  int aL = (wm * 64 + l15) * 64;
  int bL = (wn * 32 + l15) * 64;
  int x7 = l15 & 7;
  int colx0 = ((l4) ^ x7) * 8;
  int colx1 = ((4 + l4) ^ x7) * 8;

  f32x4 acc[8][4] = {};
  BF8 af[2][2];   // current m-pair A frags
  BF8 bf[4][2];   // full-tile B frags (all 4 n)

#define MFMA_(a_, b_, c_) __builtin_amdgcn_mfma_f32_16x16x32_bf16((a_), (b_), (c_), 0, 0, 0)
#define BAR() asm volatile("s_barrier" ::: "memory")
#define LGK0() asm volatile("s_waitcnt lgkmcnt(0)" ::: "memory")
#define PRIO1 __builtin_amdgcn_s_setprio(1)
#define PRIO0 __builtin_amdgcn_s_setprio(0)
#define VMC(n_) asm volatile("s_waitcnt vmcnt(" #n_ ")" ::: "memory")

#define STAGE_A(t_, h_) { int bo_ = ((t_) & 1) * 16384 + (h_) * 8192 + w * 512; \
    const ushort* gp_ = Ab + (size_t)(arow0 + (h_) * 64) * Rn + (t_) * 64 + srcC; \
    glds(gp_, As + bo_); \
    glds(gp_ + 128 * (size_t)Rn, As + bo_ + 4096); }
#define STAGE_B(t_, h_) { int bo_ = ((t_) & 1) * 16384 + (h_) * 8192 + w * 512; \
    const ushort* gp_ = Bb + (size_t)(brow0 + (h_) * 32) * Rn + (t_) * 64 + srcC; \
    glds(gp_, Bs + bo_); \
    glds(gp_ + 128 * (size_t)Rn, Bs + bo_ + 4096); }

#define RD_A2(mp_, bo_) { _Pragma("unroll") for (int mm = 0; mm < 2; mm++) { \
    int ba_ = (bo_) + ((mp_) >> 1) * 8192 + aL + (((mp_) & 1) * 2 + mm) * 1024; \
    af[mm][0].q = *(const uint4*)&As[ba_ + colx0]; \
    af[mm][1].q = *(const uint4*)&As[ba_ + colx1]; } }
#define RD_B_ALL(bo_) { _Pragma("unroll") for (int n = 0; n < 4; n++) { \
    int bb_ = (bo_) + (n >> 1) * 8192 + bL + (n & 1) * 1024; \
    bf[n][0].q = *(const uint4*)&Bs[bb_ + colx0]; \
    bf[n][1].q = *(const uint4*)&Bs[bb_ + colx1]; } }
#define MM2(mp_) { _Pragma("unroll") for (int ks = 0; ks < 2; ks++) \
    _Pragma("unroll") for (int mm = 0; mm < 2; mm++) \
      _Pragma("unroll") for (int n = 0; n < 4; n++) \
        acc[(mp_) * 2 + mm][n] = MFMA_(af[mm][ks].v, bf[n][ks].v, acc[(mp_) * 2 + mm][n]); }

  // prologue: tile0 (4 halves) + tile1 {A0,B0,B1} in steady-state queue order.
  STAGE_A(0, 0); STAGE_B(0, 0); STAGE_B(0, 1); STAGE_A(0, 1);
  STAGE_A(1, 0); STAGE_B(1, 0); STAGE_B(1, 1);
  VMC(6); BAR();   // tile0 landed; [A0,B0,B1](1) in flight

#define TILE(t_, SA1_, SN2_, WTAIL_) { \
    int cur = ((t_) & 1) * 16384; \
    /* P0: m-pair0 x all-n; reads 4A+8B; stage A1(t+1) */ \
    RD_A2(0, cur); RD_B_ALL(cur); \
    if (SA1_) STAGE_A((t_) + 1, 1); \
    BAR(); LGK0(); PRIO1; MM2(0); PRIO0; BAR(); \
    /* P1: m-pair1; 4 reads; stage A0(t+2) */ \
    RD_A2(1, cur); \
    if (SN2_) STAGE_A((t_) + 2, 0); \
    BAR(); LGK0(); PRIO1; MM2(1); PRIO0; BAR(); \
    /* P2: m-pair2; 4 reads; stage B0(t+2) */ \
    RD_A2(2, cur); \
    if (SN2_) STAGE_B((t_) + 2, 0); \
    BAR(); LGK0(); PRIO1; MM2(2); PRIO0; BAR(); \
    /* P3: m-pair3; 4 reads; stage B1(t+2); counted vmcnt */ \
    RD_A2(3, cur); \
    if (SN2_) STAGE_B((t_) + 2, 1); \
    WTAIL_; \
    BAR(); LGK0(); PRIO1; MM2(3); PRIO0; BAR(); \
  }

  for (int t = 0; t <= NT - 3; ++t)
    TILE(t, 1, 1, VMC(6));
  TILE(NT - 2, 1, 0, VMC(0));
  TILE(NT - 1, 0, 0, (void)0);

#undef TILE
#undef MM2
#undef RD_B_ALL
#undef RD_A2
#undef STAGE_B
#undef STAGE_A

  float* ob = out + (size_t)b * Nn * Cn;
#pragma unroll
  for (int m = 0; m < 8; m++) {
    int i = i0 + wm * 128 + m * 16 + l4 * 4;
#pragma unroll
    for (int n = 0; n < 4; n++) {
      int c = c0 + wn * 64 + n * 16 + l15;
#pragma unroll
      for (int q = 0; q < 4; q++)
        ob[(size_t)(i + q) * Cn + c] = fmaxf(acc[m][n][q], 0.0f);
    }
  }
}

extern "C" void kernel_launch(void* const* d_in, const int* in_sizes, int n_in,
                              void* d_out, int out_size, void* d_ws, size_t ws_size,
                              hipStream_t stream) {
  const float* x     = (const float*)d_in[0];  // (B,N,F,T)
  const float* att   = (const float*)d_in[1];  // (B,N,N)
  const float* cheb  = (const float*)d_in[2];  // (K,N,N)
  const float* Theta = (const float*)d_in[3];  // (K,F,O)
  float* out = (float*)d_out;                  // (B,N,O,T)

  char* ws = (char*)d_ws;
  ushort* ThT = (ushort*)ws;
  ushort* Wt  = (ushort*)(ws + 65536);
  ushort* Yt  = (ushort*)(ws + 65536 + 50331648ull);

  hipFuncSetAttribute((const void*)k_gemm, hipFuncAttributeMaxDynamicSharedMemorySize, 131072);

  k_thetaT<<<48, 256, 0, stream>>>(Theta, ThT);
  k_prepW<<<dim3(16, 32), 256, 0, stream>>>(att, cheb, Wt);
  k_prepY<<<dim3(32, 8), 512, 0, stream>>>(x, ThT, Yt);
  k_gemm<<<256, 512, 131072, stream>>>(Wt, Yt, out);
}

// Round 12
// 161.434 us; speedup vs baseline: 1.1212x; 1.1212x over previous
//
#include <hip/hip_runtime.h>
#include <stdint.h>

#define Bn 8
#define Nn 1024
#define Fn 64
#define Tn 32
#define Kn 3
#define On 64
#define Rn (Kn * Nn)   // 3072 reduction dim (k,j)
#define Cn (On * Tn)   // 2048 output cols (o,t)
#define NT (Rn / 64)   // 48 K-tiles of BK=64

typedef __bf16 bf16x8 __attribute__((ext_vector_type(8)));
typedef float f32x4 __attribute__((ext_vector_type(4)));
typedef __attribute__((address_space(1))) void gvoid;
typedef __attribute__((address_space(3))) void lvoid;

union BF8 { bf16x8 v; ushort s[8]; uint4 q; };

static __device__ __forceinline__ ushort f2bf(float f) {
  uint32_t u = __float_as_uint(f);
  return (ushort)((u + 0x7FFFu + ((u >> 16) & 1u)) >> 16);
}

static __device__ __forceinline__ void glds(const ushort* g, ushort* l) {
  __builtin_amdgcn_global_load_lds((gvoid*)g, (lvoid*)l, 16, 0, 0);
}

// K1: Wt[b][i][k*Nn+j] = cheb[k][j][i] * att[b][j][i], bf16 (R9 measured version).
// Block (0,0) additionally builds ThT[k][o][f] = Theta[k][f][o] (consumed by
// k_prepY, which is stream-ordered after this kernel) — saves one launch.
__global__ __launch_bounds__(256) void k_prepW(const float* __restrict__ att,
                                               const float* __restrict__ cheb,
                                               const float* __restrict__ Theta,
                                               ushort* __restrict__ Wt,
                                               ushort* __restrict__ ThT) {
  __shared__ float chebT[Kn][64][33];
  __shared__ float attT[64][33];
  int i0 = blockIdx.x * 64, j0 = blockIdx.y * 32;
  int tid = threadIdx.x;
  int il = tid & 63, jr = tid >> 6;
  int jc = tid & 3, iw = tid >> 2;

  if (blockIdx.x == 0 && blockIdx.y == 0) {
    for (int idx = tid; idx < Kn * On * Fn; idx += 256) {
      int k = idx / (On * Fn);
      int rem = idx % (On * Fn);
      int o = rem / Fn, f = rem % Fn;
      ThT[idx] = f2bf(Theta[(k * Fn + f) * On + o]);
    }
  }

#pragma unroll
  for (int k = 0; k < Kn; k++)
#pragma unroll
    for (int p = 0; p < 8; p++) {
      int j = jr + p * 4;
      chebT[k][il][j] = cheb[((size_t)k * Nn + j0 + j) * Nn + i0 + il];
    }

  for (int b = 0; b < Bn; b++) {
    __syncthreads();
#pragma unroll
    for (int p = 0; p < 8; p++) {
      int j = jr + p * 4;
      attT[il][j] = att[((size_t)b * Nn + j0 + j) * Nn + i0 + il];
    }
    __syncthreads();
#pragma unroll
    for (int k = 0; k < Kn; k++) {
      ushort tmp[8];
#pragma unroll
      for (int q = 0; q < 8; q++)
        tmp[q] = f2bf(attT[iw][jc * 8 + q] * chebT[k][iw][jc * 8 + q]);
      *(uint4*)&Wt[((size_t)b * Nn + i0 + iw) * Rn + (size_t)k * Nn + j0 + jc * 8] =
          *(const uint4*)tmp;
    }
  }
}

// K2: Y_T[b][c][k*Nn+j] = sum_f ThT[k][o][f]*x[b][j][f][t].
// R11 measured version: jj-pair batching, packed ds_write_b32, uint4 global writes.
__global__ __launch_bounds__(512) void k_prepY(const float* __restrict__ x,
                                               const ushort* __restrict__ ThT,
                                               ushort* __restrict__ Yt) {
  __shared__ ushort ylds[1024 * 32];
  int jt = blockIdx.x, b = blockIdx.y;
  int j0 = jt * 32;
  int tid = threadIdx.x;
  int lane = tid & 63, w = tid >> 6;
  int l15 = lane & 15, l4 = lane >> 4;

  BF8 bfr[4][2][2];
#pragma unroll
  for (int jj = 0; jj < 4; jj++) {
    const float* xp = x + ((size_t)b * Nn + (j0 + w * 4 + jj)) * (Fn * Tn);
#pragma unroll
    for (int ks = 0; ks < 2; ks++)
#pragma unroll
      for (int tf = 0; tf < 2; tf++) {
        int t = tf * 16 + l15;
        int fb = ks * 32 + l4 * 8;
#pragma unroll
        for (int e = 0; e < 8; e++)
          bfr[jj][ks][tf].s[e] = f2bf(xp[(fb + e) * Tn + t]);
      }
  }

  for (int k = 0; k < Kn; k++) {
    for (int h = 0; h < 2; h++) {
      BF8 afr[2][2];
#pragma unroll
      for (int o2 = 0; o2 < 2; o2++)
#pragma unroll
        for (int ks = 0; ks < 2; ks++) {
          int o = h * 32 + o2 * 16 + l15;
          afr[o2][ks].q = *(const uint4*)&ThT[((size_t)k * On + o) * Fn + ks * 32 + l4 * 8];
        }
      uint32_t* y32 = (uint32_t*)ylds;
#pragma unroll
      for (int jp = 0; jp < 2; jp++) {
        f32x4 acc[2][2][2] = {};  // [j2][o2][tf]
#pragma unroll
        for (int j2 = 0; j2 < 2; j2++)
#pragma unroll
          for (int ks = 0; ks < 2; ks++)
#pragma unroll
            for (int o2 = 0; o2 < 2; o2++)
#pragma unroll
              for (int tf = 0; tf < 2; tf++)
                acc[j2][o2][tf] = __builtin_amdgcn_mfma_f32_16x16x32_bf16(
                    afr[o2][ks].v, bfr[jp * 2 + j2][ks][tf].v, acc[j2][o2][tf], 0, 0, 0);
#pragma unroll
        for (int o2 = 0; o2 < 2; o2++)
#pragma unroll
          for (int tf = 0; tf < 2; tf++)
#pragma unroll
            for (int q = 0; q < 4; q++) {
              int cl = (o2 * 16 + l4 * 4 + q) * Tn + tf * 16 + l15;
              uint32_t pk = (uint32_t)f2bf(acc[0][o2][tf][q]) |
                            ((uint32_t)f2bf(acc[1][o2][tf][q]) << 16);
              y32[cl * 16 + w * 2 + jp] = pk;
            }
      }
      __syncthreads();
      const uint4* yl4 = (const uint4*)ylds;
      uint4* Yt4 = (uint4*)Yt;
      int e4 = tid & 3, r4 = tid >> 2;
      for (int pass = 0; pass < 8; pass++) {
        int cl = pass * 128 + r4;
        size_t off = ((size_t)b * Cn + (size_t)(h * 1024 + cl)) * Rn + (size_t)k * Nn + j0;
        Yt4[off / 8 + e4] = yl4[cl * 4 + e4];
      }
      __syncthreads();
    }
  }
}

// K3: 256x256 tile, BK=64, 8 waves (2Mx4N), 2-deep K-tile dbuf, XOR-swizzled LDS.
// R5 EXACT — PINNED (measured 96.0/96.3/96.6 us, MfmaUtil 47.5%, 0 bank
// conflicts across R5/R9/R10). Six barrier-phase schedule variants (R4,R6,R7,
// R8,R11) all landed 108-129 us — do not revisit that family.
__global__ __launch_bounds__(512, 2) void k_gemm(const ushort* __restrict__ Wt,
                                                 const ushort* __restrict__ Yt,
                                                 float* __restrict__ out) {
  extern __shared__ __align__(16) ushort smem[];
  ushort* As = smem;           // 2 bufs x 2 halves x 128x64
  ushort* Bs = smem + 32768;

  int g = blockIdx.x;
  int b = g & 7, slot = g >> 3;
  int i0 = (slot & 3) * 256, c0 = (slot >> 2) * 256;
  int tid = threadIdx.x, lane = tid & 63, w = tid >> 6;
  int l15 = lane & 15, l4 = lane >> 4;
  int wm = w >> 2, wn = w & 3;

  const ushort* Ab = Wt + ((size_t)b * Nn + i0) * Rn;
  const ushort* Bb = Yt + ((size_t)b * Cn + c0) * Rn;

  int srcC = (((lane & 7) ^ (lane >> 3)) * 8);
  int arow0 = w * 8 + (lane >> 3);
  int brow0 = (w >> 2) * 64 + (w & 3) * 8 + (lane >> 3);

  int aL = (wm * 64 + l15) * 64;
  int bL = (wn * 32 + l15) * 64;
  int x7 = l15 & 7;
  int colx0 = ((l4) ^ x7) * 8;
  int colx1 = ((4 + l4) ^ x7) * 8;

  f32x4 acc[8][4] = {};
  BF8 afX[4][2], afY[4][2];
  BF8 bfX[2][2], bfY[2][2];

#define MFMA_(a_, b_, c_) __builtin_amdgcn_mfma_f32_16x16x32_bf16((a_), (b_), (c_), 0, 0, 0)
#define BAR() asm volatile("s_barrier" ::: "memory")
#define PRIO1 __builtin_amdgcn_s_setprio(1)
#define PRIO0 __builtin_amdgcn_s_setprio(0)
#define VMC(n_) asm volatile("s_waitcnt vmcnt(" #n_ ")" ::: "memory")

#define STAGE_A(t_, h_) { int bo_ = ((t_) & 1) * 16384 + (h_) * 8192 + w * 512; \
    const ushort* gp_ = Ab + (size_t)(arow0 + (h_) * 64) * Rn + (t_) * 64 + srcC; \
    glds(gp_, As + bo_); \
    glds(gp_ + 128 * (size_t)Rn, As + bo_ + 4096); }
#define STAGE_B(t_, h_) { int bo_ = ((t_) & 1) * 16384 + (h_) * 8192 + w * 512; \
    const ushort* gp_ = Bb + (size_t)(brow0 + (h_) * 32) * Rn + (t_) * 64 + srcC; \
    glds(gp_, Bs + bo_); \
    glds(gp_ + 128 * (size_t)Rn, Bs + bo_ + 4096); }

#define RD_A(DST_, bo_, mh_) { _Pragma("unroll") for (int m = 0; m < 4; m++) { \
    int ba_ = (bo_) + (mh_) * 8192 + aL + m * 1024; \
    DST_[m][0].q = *(const uint4*)&As[ba_ + colx0]; \
    DST_[m][1].q = *(const uint4*)&As[ba_ + colx1]; } }
#define RD_B(DST_, bo_, nh_) { _Pragma("unroll") for (int n = 0; n < 2; n++) { \
    int bb_ = (bo_) + (nh_) * 8192 + bL + n * 1024; \
    DST_[n][0].q = *(const uint4*)&Bs[bb_ + colx0]; \
    DST_[n][1].q = *(const uint4*)&Bs[bb_ + colx1]; } }

#define MMC(AF_, BF_, MO_, NO_) { _Pragma("unroll") for (int ks = 0; ks < 2; ks++) \
    _Pragma("unroll") for (int m = 0; m < 4; m++) \
      _Pragma("unroll") for (int n = 0; n < 2; n++) \
        acc[(MO_) + m][(NO_) + n] = MFMA_(AF_[m][ks].v, BF_[n][ks].v, acc[(MO_) + m][(NO_) + n]); }

  STAGE_A(0, 0); STAGE_B(0, 0); STAGE_B(0, 1); STAGE_A(0, 1); STAGE_A(1, 0);
  VMC(6); BAR();
  RD_A(afX, 0, 0); RD_B(bfX, 0, 0);

#define TILE(t_, S0_, S1_, S2_, W0_, W1_, W3_, LAST_) { \
    int bo_c = ((t_) & 1) * 16384; \
    VMC(W0_); BAR(); \
    RD_B(bfY, bo_c, 1); \
    if (S0_) STAGE_B((t_) + 1, 0); \
    PRIO1; MMC(afX, bfX, 0, 0); PRIO0; \
    VMC(W1_); BAR(); \
    RD_A(afY, bo_c, 1); \
    if (S1_) { STAGE_B((t_) + 1, 1); STAGE_A((t_) + 1, 1); } \
    PRIO1; MMC(afX, bfY, 0, 2); PRIO0; \
    if (S2_) STAGE_A((t_) + 2, 0); \
    PRIO1; MMC(afY, bfX, 4, 0); PRIO0; \
    if (!(LAST_)) { VMC(W3_); BAR(); \
      RD_A(afX, bo_c ^ 16384, 0); RD_B(bfX, bo_c ^ 16384, 0); } \
    PRIO1; MMC(afY, bfY, 4, 2); PRIO0; \
  }

  for (int t = 0; t < NT - 2; ++t)
    TILE(t, 1, 1, 1, 4, 4, 6, 0);
  TILE(NT - 2, 1, 1, 0, 4, 4, 4, 0);
  TILE(NT - 1, 0, 0, 0, 2, 0, 0, 1);

#undef TILE
#undef MMC
#undef RD_B
#undef RD_A
#undef STAGE_B
#undef STAGE_A
#undef VMC

  float* ob = out + (size_t)b * Nn * Cn;
#pragma unroll
  for (int m = 0; m < 8; m++) {
    int i = i0 + wm * 128 + m * 16 + l4 * 4;
#pragma unroll
    for (int n = 0; n < 4; n++) {
      int c = c0 + wn * 64 + n * 16 + l15;
#pragma unroll
      for (int q = 0; q < 4; q++)
        ob[(size_t)(i + q) * Cn + c] = fmaxf(acc[m][n][q], 0.0f);
    }
  }
}

extern "C" void kernel_launch(void* const* d_in, const int* in_sizes, int n_in,
                              void* d_out, int out_size, void* d_ws, size_t ws_size,
                              hipStream_t stream) {
  const float* x     = (const float*)d_in[0];  // (B,N,F,T)
  const float* att   = (const float*)d_in[1];  // (B,N,N)
  const float* cheb  = (const float*)d_in[2];  // (K,N,N)
  const float* Theta = (const float*)d_in[3];  // (K,F,O)
  float* out = (float*)d_out;                  // (B,N,O,T)

  char* ws = (char*)d_ws;
  ushort* ThT = (ushort*)ws;
  ushort* Wt  = (ushort*)(ws + 65536);
  ushort* Yt  = (ushort*)(ws + 65536 + 50331648ull);

  hipFuncSetAttribute((const void*)k_gemm, hipFuncAttributeMaxDynamicSharedMemorySize, 131072);

  k_prepW<<<dim3(16, 32), 256, 0, stream>>>(att, cheb, Theta, Wt, ThT);
  k_prepY<<<dim3(32, 8), 512, 0, stream>>>(x, ThT, Yt);
  k_gemm<<<256, 512, 131072, stream>>>(Wt, Yt, out);
}

// Round 13
// 153.174 us; speedup vs baseline: 1.1817x; 1.0539x over previous
//
#include <hip/hip_runtime.h>
#include <stdint.h>

#define Bn 8
#define Nn 1024
#define Fn 64
#define Tn 32
#define Kn 3
#define On 64
#define Rn (Kn * Nn)   // 3072 reduction dim (k,j)
#define Cn (On * Tn)   // 2048 output cols (o,t)
#define NT (Rn / 64)   // 48 K-tiles of BK=64

typedef __bf16 bf16x8 __attribute__((ext_vector_type(8)));
typedef float f32x4 __attribute__((ext_vector_type(4)));
typedef __attribute__((address_space(1))) void gvoid;
typedef __attribute__((address_space(3))) void lvoid;

union BF8 { bf16x8 v; ushort s[8]; uint4 q; };

static __device__ __forceinline__ ushort f2bf(float f) {
  uint32_t u = __float_as_uint(f);
  return (ushort)((u + 0x7FFFu + ((u >> 16) & 1u)) >> 16);
}

static __device__ __forceinline__ void glds(const ushort* g, ushort* l) {
  __builtin_amdgcn_global_load_lds((gvoid*)g, (lvoid*)l, 16, 0, 0);
}

// K0: ThetaT[k][o][f] = Theta[k][f][o], bf16. Separate kernel — R12 showed
// folding this into one prepW block creates an ~8us straggler.
__global__ void k_thetaT(const float* __restrict__ Theta, ushort* __restrict__ ThT) {
  int idx = blockIdx.x * 256 + threadIdx.x;
  if (idx < Kn * On * Fn) {
    int k = idx / (On * Fn);
    int rem = idx % (On * Fn);
    int o = rem / Fn, f = rem % Fn;
    ThT[idx] = f2bf(Theta[(k * Fn + f) * On + o]);
  }
}

// K1: Wt[b][i][k*Nn+j] = cheb[k][j][i] * att[b][j][i], bf16 (R9 measured version).
__global__ __launch_bounds__(256) void k_prepW(const float* __restrict__ att,
                                               const float* __restrict__ cheb,
                                               ushort* __restrict__ Wt) {
  __shared__ float chebT[Kn][64][33];
  __shared__ float attT[64][33];
  int i0 = blockIdx.x * 64, j0 = blockIdx.y * 32;
  int tid = threadIdx.x;
  int il = tid & 63, jr = tid >> 6;
  int jc = tid & 3, iw = tid >> 2;

#pragma unroll
  for (int k = 0; k < Kn; k++)
#pragma unroll
    for (int p = 0; p < 8; p++) {
      int j = jr + p * 4;
      chebT[k][il][j] = cheb[((size_t)k * Nn + j0 + j) * Nn + i0 + il];
    }

  for (int b = 0; b < Bn; b++) {
    __syncthreads();
#pragma unroll
    for (int p = 0; p < 8; p++) {
      int j = jr + p * 4;
      attT[il][j] = att[((size_t)b * Nn + j0 + j) * Nn + i0 + il];
    }
    __syncthreads();
#pragma unroll
    for (int k = 0; k < Kn; k++) {
      ushort tmp[8];
#pragma unroll
      for (int q = 0; q < 8; q++)
        tmp[q] = f2bf(attT[iw][jc * 8 + q] * chebT[k][iw][jc * 8 + q]);
      *(uint4*)&Wt[((size_t)b * Nn + i0 + iw) * Rn + (size_t)k * Nn + j0 + jc * 8] =
          *(const uint4*)tmp;
    }
  }
}

// K2: Y_T[b][c][k*Nn+j] = sum_f ThT[k][o][f]*x[b][j][f][t].
// R11 measured version: jj-pair batching, packed ds_write_b32, uint4 global writes.
__global__ __launch_bounds__(512) void k_prepY(const float* __restrict__ x,
                                               const ushort* __restrict__ ThT,
                                               ushort* __restrict__ Yt) {
  __shared__ ushort ylds[1024 * 32];
  int jt = blockIdx.x, b = blockIdx.y;
  int j0 = jt * 32;
  int tid = threadIdx.x;
  int lane = tid & 63, w = tid >> 6;
  int l15 = lane & 15, l4 = lane >> 4;

  BF8 bfr[4][2][2];
#pragma unroll
  for (int jj = 0; jj < 4; jj++) {
    const float* xp = x + ((size_t)b * Nn + (j0 + w * 4 + jj)) * (Fn * Tn);
#pragma unroll
    for (int ks = 0; ks < 2; ks++)
#pragma unroll
      for (int tf = 0; tf < 2; tf++) {
        int t = tf * 16 + l15;
        int fb = ks * 32 + l4 * 8;
#pragma unroll
        for (int e = 0; e < 8; e++)
          bfr[jj][ks][tf].s[e] = f2bf(xp[(fb + e) * Tn + t]);
      }
  }

  for (int k = 0; k < Kn; k++) {
    for (int h = 0; h < 2; h++) {
      BF8 afr[2][2];
#pragma unroll
      for (int o2 = 0; o2 < 2; o2++)
#pragma unroll
        for (int ks = 0; ks < 2; ks++) {
          int o = h * 32 + o2 * 16 + l15;
          afr[o2][ks].q = *(const uint4*)&ThT[((size_t)k * On + o) * Fn + ks * 32 + l4 * 8];
        }
      uint32_t* y32 = (uint32_t*)ylds;
#pragma unroll
      for (int jp = 0; jp < 2; jp++) {
        f32x4 acc[2][2][2] = {};  // [j2][o2][tf]
#pragma unroll
        for (int j2 = 0; j2 < 2; j2++)
#pragma unroll
          for (int ks = 0; ks < 2; ks++)
#pragma unroll
            for (int o2 = 0; o2 < 2; o2++)
#pragma unroll
              for (int tf = 0; tf < 2; tf++)
                acc[j2][o2][tf] = __builtin_amdgcn_mfma_f32_16x16x32_bf16(
                    afr[o2][ks].v, bfr[jp * 2 + j2][ks][tf].v, acc[j2][o2][tf], 0, 0, 0);
#pragma unroll
        for (int o2 = 0; o2 < 2; o2++)
#pragma unroll
          for (int tf = 0; tf < 2; tf++)
#pragma unroll
            for (int q = 0; q < 4; q++) {
              int cl = (o2 * 16 + l4 * 4 + q) * Tn + tf * 16 + l15;
              uint32_t pk = (uint32_t)f2bf(acc[0][o2][tf][q]) |
                            ((uint32_t)f2bf(acc[1][o2][tf][q]) << 16);
              y32[cl * 16 + w * 2 + jp] = pk;
            }
      }
      __syncthreads();
      const uint4* yl4 = (const uint4*)ylds;
      uint4* Yt4 = (uint4*)Yt;
      int e4 = tid & 3, r4 = tid >> 2;
      for (int pass = 0; pass < 8; pass++) {
        int cl = pass * 128 + r4;
        size_t off = ((size_t)b * Cn + (size_t)(h * 1024 + cl)) * Rn + (size_t)k * Nn + j0;
        Yt4[off / 8 + e4] = yl4[cl * 4 + e4];
      }
      __syncthreads();
    }
  }
}

// K3: 256x256 tile, BK=64, 8 waves (2Mx4N), 2-deep K-tile dbuf, XOR-swizzled LDS.
// R5 EXACT — PINNED (measured 96.0/96.3/96.4/96.6 us across R5/R9/R10/R12).
// Six barrier-phase schedule variants (R4,R6,R7,R8,R11) all landed 108-129 us.
__global__ __launch_bounds__(512, 2) void k_gemm(const ushort* __restrict__ Wt,
                                                 const ushort* __restrict__ Yt,
                                                 float* __restrict__ out) {
  extern __shared__ __align__(16) ushort smem[];
  ushort* As = smem;           // 2 bufs x 2 halves x 128x64
  ushort* Bs = smem + 32768;

  int g = blockIdx.x;
  int b = g & 7, slot = g >> 3;
  int i0 = (slot & 3) * 256, c0 = (slot >> 2) * 256;
  int tid = threadIdx.x, lane = tid & 63, w = tid >> 6;
  int l15 = lane & 15, l4 = lane >> 4;
  int wm = w >> 2, wn = w & 3;

  const ushort* Ab = Wt + ((size_t)b * Nn + i0) * Rn;
  const ushort* Bb = Yt + ((size_t)b * Cn + c0) * Rn;

  int srcC = (((lane & 7) ^ (lane >> 3)) * 8);
  int arow0 = w * 8 + (lane >> 3);
  int brow0 = (w >> 2) * 64 + (w & 3) * 8 + (lane >> 3);

  int aL = (wm * 64 + l15) * 64;
  int bL = (wn * 32 + l15) * 64;
  int x7 = l15 & 7;
  int colx0 = ((l4) ^ x7) * 8;
  int colx1 = ((4 + l4) ^ x7) * 8;

  f32x4 acc[8][4] = {};
  BF8 afX[4][2], afY[4][2];
  BF8 bfX[2][2], bfY[2][2];

#define MFMA_(a_, b_, c_) __builtin_amdgcn_mfma_f32_16x16x32_bf16((a_), (b_), (c_), 0, 0, 0)
#define BAR() asm volatile("s_barrier" ::: "memory")
#define PRIO1 __builtin_amdgcn_s_setprio(1)
#define PRIO0 __builtin_amdgcn_s_setprio(0)
#define VMC(n_) asm volatile("s_waitcnt vmcnt(" #n_ ")" ::: "memory")

#define STAGE_A(t_, h_) { int bo_ = ((t_) & 1) * 16384 + (h_) * 8192 + w * 512; \
    const ushort* gp_ = Ab + (size_t)(arow0 + (h_) * 64) * Rn + (t_) * 64 + srcC; \
    glds(gp_, As + bo_); \
    glds(gp_ + 128 * (size_t)Rn, As + bo_ + 4096); }
#define STAGE_B(t_, h_) { int bo_ = ((t_) & 1) * 16384 + (h_) * 8192 + w * 512; \
    const ushort* gp_ = Bb + (size_t)(brow0 + (h_) * 32) * Rn + (t_) * 64 + srcC; \
    glds(gp_, Bs + bo_); \
    glds(gp_ + 128 * (size_t)Rn, Bs + bo_ + 4096); }

#define RD_A(DST_, bo_, mh_) { _Pragma("unroll") for (int m = 0; m < 4; m++) { \
    int ba_ = (bo_) + (mh_) * 8192 + aL + m * 1024; \
    DST_[m][0].q = *(const uint4*)&As[ba_ + colx0]; \
    DST_[m][1].q = *(const uint4*)&As[ba_ + colx1]; } }
#define RD_B(DST_, bo_, nh_) { _Pragma("unroll") for (int n = 0; n < 2; n++) { \
    int bb_ = (bo_) + (nh_) * 8192 + bL + n * 1024; \
    DST_[n][0].q = *(const uint4*)&Bs[bb_ + colx0]; \
    DST_[n][1].q = *(const uint4*)&Bs[bb_ + colx1]; } }

#define MMC(AF_, BF_, MO_, NO_) { _Pragma("unroll") for (int ks = 0; ks < 2; ks++) \
    _Pragma("unroll") for (int m = 0; m < 4; m++) \
      _Pragma("unroll") for (int n = 0; n < 2; n++) \
        acc[(MO_) + m][(NO_) + n] = MFMA_(AF_[m][ks].v, BF_[n][ks].v, acc[(MO_) + m][(NO_) + n]); }

  STAGE_A(0, 0); STAGE_B(0, 0); STAGE_B(0, 1); STAGE_A(0, 1); STAGE_A(1, 0);
  VMC(6); BAR();
  RD_A(afX, 0, 0); RD_B(bfX, 0, 0);

#define TILE(t_, S0_, S1_, S2_, W0_, W1_, W3_, LAST_) { \
    int bo_c = ((t_) & 1) * 16384; \
    VMC(W0_); BAR(); \
    RD_B(bfY, bo_c, 1); \
    if (S0_) STAGE_B((t_) + 1, 0); \
    PRIO1; MMC(afX, bfX, 0, 0); PRIO0; \
    VMC(W1_); BAR(); \
    RD_A(afY, bo_c, 1); \
    if (S1_) { STAGE_B((t_) + 1, 1); STAGE_A((t_) + 1, 1); } \
    PRIO1; MMC(afX, bfY, 0, 2); PRIO0; \
    if (S2_) STAGE_A((t_) + 2, 0); \
    PRIO1; MMC(afY, bfX, 4, 0); PRIO0; \
    if (!(LAST_)) { VMC(W3_); BAR(); \
      RD_A(afX, bo_c ^ 16384, 0); RD_B(bfX, bo_c ^ 16384, 0); } \
    PRIO1; MMC(afY, bfY, 4, 2); PRIO0; \
  }

  for (int t = 0; t < NT - 2; ++t)
    TILE(t, 1, 1, 1, 4, 4, 6, 0);
  TILE(NT - 2, 1, 1, 0, 4, 4, 4, 0);
  TILE(NT - 1, 0, 0, 0, 2, 0, 0, 1);

#undef TILE
#undef MMC
#undef RD_B
#undef RD_A
#undef STAGE_B
#undef STAGE_A
#undef VMC

  float* ob = out + (size_t)b * Nn * Cn;
#pragma unroll
  for (int m = 0; m < 8; m++) {
    int i = i0 + wm * 128 + m * 16 + l4 * 4;
#pragma unroll
    for (int n = 0; n < 4; n++) {
      int c = c0 + wn * 64 + n * 16 + l15;
#pragma unroll
      for (int q = 0; q < 4; q++)
        ob[(size_t)(i + q) * Cn + c] = fmaxf(acc[m][n][q], 0.0f);
    }
  }
}

extern "C" void kernel_launch(void* const* d_in, const int* in_sizes, int n_in,
                              void* d_out, int out_size, void* d_ws, size_t ws_size,
                              hipStream_t stream) {
  const float* x     = (const float*)d_in[0];  // (B,N,F,T)
  const float* att   = (const float*)d_in[1];  // (B,N,N)
  const float* cheb  = (const float*)d_in[2];  // (K,N,N)
  const float* Theta = (const float*)d_in[3];  // (K,F,O)
  float* out = (float*)d_out;                  // (B,N,O,T)

  char* ws = (char*)d_ws;
  ushort* ThT = (ushort*)ws;
  ushort* Wt  = (ushort*)(ws + 65536);
  ushort* Yt  = (ushort*)(ws + 65536 + 50331648ull);

  hipFuncSetAttribute((const void*)k_gemm, hipFuncAttributeMaxDynamicSharedMemorySize, 131072);

  k_thetaT<<<48, 256, 0, stream>>>(Theta, ThT);
  k_prepW<<<dim3(16, 32), 256, 0, stream>>>(att, cheb, Wt);
  k_prepY<<<dim3(32, 8), 512, 0, stream>>>(x, ThT, Yt);
  k_gemm<<<256, 512, 131072, stream>>>(Wt, Yt, out);
}